// Round 5
// baseline (313.841 us; speedup 1.0000x reference)
//
#include <hip/hip_runtime.h>

// SigWassersteinMetric: depth-4 path signature, C=10, T=256.
//   original: (4096, 256, 10) f32; generated: (1024, 256, 10) f32; sample_idx: (1024,)
//
// ROUND-19: register extraction of lane-varying values (via/vk0/vk1).
//   - R18 FAILED (218us): SMEM shares lgkmcnt with ds_read, out-of-order ->
//     compiler emits lgkmcnt(0) per consumer -> SMEM latency exposed per step.
//   - Calibrated pipe model (R14/R16/R17 all within 5%): LDS pipe is per-CU
//     (shared by 4 SIMDs), VALU per-SIMD. R17: LDS 57cyc x32 waves = 1824/CU
//     (binding, = 194us); VALU 136cyc x8 = 1088/SIMD.
//   - This round: via=vv[ia], vk0=vv[k0], vk1=vv[k0+5] are elements of the
//     uniform row ALREADY in registers (va/vb/vc). Extract them with cndmask
//     chains whose compare masks are loop-invariant (hoisted bools -> SGPR
//     pairs). Trades 17.4 LDS cyc (x32) for 34 VALU cyc (x8):
//       LDS -> 40x32 = 1280/CU ; VALU -> 170x8 = 1360/SIMD (new bound)
//     Predicted accum ~150us, VALUBusy ~90%. vjp stays on LDS (extracting it
//     too would push VALU to 1488 -- worse).
//
// Horner-factored Chen step (verified rounds 2/4-13):
//   A2 = S2 + (S1 + v/4) (x) v/3 ;  B2 = S2 + (S1 + v/3) (x) v/2
//   A3 = S3 + A2 (x) v/2 ;  S4' = S4 + A3 (x) v ;  S3' = S3 + B2 (x) v
//   S2' = S2 + (S1 + v/2) (x) v ;  S1 closed-form in epilogue.
#define T_LEN 256
#define C_DIM 10
#define NSTEP 255
#define BSZ   1024
#define NPAIR 1024
#define D1 10
#define D2 100
#define D3 1000
#define DTOT 11110
#define PATH_ELEMS (T_LEN * C_DIM)   // 2560
#define DX_ELEMS (NSTEP * C_DIM)     // 2550
#define DXROW 12                     // padded dx row stride (48 B, 16B-aligned)

typedef float f32x2 __attribute__((ext_vector_type(2)));
typedef float f32x4 __attribute__((ext_vector_type(4)));

// d += bcast(a.lo) * b
#define PK_FMA_B0(d, a, b) \
    asm("v_pk_fma_f32 %0, %1, %2, %0 op_sel:[0,0,0] op_sel_hi:[0,1,1]" \
        : "+v"(d) : "v"(a), "v"(b))
// d += bcast(a.hi) * b
#define PK_FMA_B1(d, a, b) \
    asm("v_pk_fma_f32 %0, %1, %2, %0 op_sel:[1,0,0] op_sel_hi:[1,1,1]" \
        : "+v"(d) : "v"(a), "v"(b))
// d = bcast(a.lo) * b + c
#define PK_FMA_B0N(d, a, b, c) \
    asm("v_pk_fma_f32 %0, %1, %2, %3 op_sel:[0,0,0] op_sel_hi:[0,1,1]" \
        : "=v"(d) : "v"(a), "v"(b), "v"(c))
// d = bcast(a.hi) * b + c
#define PK_FMA_B1N(d, a, b, c) \
    asm("v_pk_fma_f32 %0, %1, %2, %3 op_sel:[1,0,0] op_sel_hi:[1,1,1]" \
        : "=v"(d) : "v"(a), "v"(b), "v"(c))
// d = a * bcast(b.lo) + c   (src1 broadcast)
#define PK_FMA_S1B0N(d, a, b, c) \
    asm("v_pk_fma_f32 %0, %1, %2, %3 op_sel:[0,0,0] op_sel_hi:[1,0,1]" \
        : "=v"(d) : "v"(a), "v"(b), "v"(c))
// d = a * bcast(b.hi) + c
#define PK_FMA_S1B1N(d, a, b, c) \
    asm("v_pk_fma_f32 %0, %1, %2, %3 op_sel:[0,1,0] op_sel_hi:[1,1,1]" \
        : "=v"(d) : "v"(a), "v"(b), "v"(c))
// d += a * bcast(b.lo)
#define PK_FMA_S1B0(d, a, b) \
    asm("v_pk_fma_f32 %0, %1, %2, %0 op_sel:[0,0,0] op_sel_hi:[1,0,1]" \
        : "+v"(d) : "v"(a), "v"(b))
// d += a * bcast(b.hi)
#define PK_FMA_S1B1(d, a, b) \
    asm("v_pk_fma_f32 %0, %1, %2, %0 op_sel:[0,1,0] op_sel_hi:[1,1,1]" \
        : "+v"(d) : "v"(a), "v"(b))
// d = a * 0.5 (both halves)
#define PK_MUL_HALF(d, a) \
    asm("v_pk_mul_f32 %0, %1, 0.5 op_sel:[0,0] op_sel_hi:[1,0]" \
        : "=v"(d) : "v"(a))

__global__ __launch_bounds__(256)
void sig_accum_kernel(
    const float* __restrict__ original,
    const float* __restrict__ generated,
    const int* __restrict__ sample_idx,
    float* __restrict__ ws, int nrep, int store_mode)
{
    const int tid  = threadIdx.x;
    const int bp   = blockIdx.x;         // 0 .. 2*NPAIR-1
    const int b    = bp >> 1;            // pair index
    const int pass = bp & 1;             // 0 = generated (-), 1 = original (+)
    const float sgn = pass ? 1.0f : -1.0f;

    __shared__ __align__(16) float s_dx[NSTEP * DXROW];  // 12240 B

    const float* path = pass
        ? original + (size_t)sample_idx[b] * PATH_ELEMS
        : generated + (size_t)b * PATH_ELEMS;

    for (int idx = tid; idx < DX_ELEMS; idx += 256) {
        int t = idx / C_DIM, c = idx - t * C_DIM;
        s_dx[t * DXROW + c] = path[idx + C_DIM] - path[idx];
    }
    __syncthreads();

    const int mbase = 2 * tid;               // valid tid<250
    const int k0  = mbase / 100;             // 0..4
    const int ij0 = mbase - k0 * 100;        // even
    const int ia  = ij0 / 10;
    const int j0  = ij0 - ia * 10;           // even -> (j0, j0+1) same decade

    // Loop-invariant lane masks for register extraction (hoisted to SGPR
    // pairs by the compiler; each use below is a single v_cndmask).
    const bool ia1 = ia >= 1, ia2 = ia >= 2, ia3 = ia >= 3, ia4 = ia >= 4;
    const bool ia5 = ia >= 5, ia6 = ia >= 6, ia7 = ia >= 7, ia8 = ia >= 8;
    const bool ia9 = ia >= 9;
    const bool k1m = k0 >= 1, k2m = k0 >= 2, k3m = k0 >= 3, k4m = k0 >= 4;

    float s1a = 0.0f;
    f32x2 s2p = {0.0f, 0.0f};                 // (q0, q1)
    f32x2 s3p[2] = {{0.0f, 0.0f}, {0.0f, 0.0f}};  // [0]=(q0,q1)@k0, [1]=@k1
    f32x2 acc2[4][5];                         // [0]=q0k0 [1]=q1k0 [2]=q0k1 [3]=q1k1
    #pragma unroll
    for (int r = 0; r < 4; ++r)
        #pragma unroll
        for (int i = 0; i < 5; ++i) acc2[r][i] = (f32x2){0.0f, 0.0f};

    if (tid < 250) {
        const float* vrow = s_dx;
        #pragma unroll 2
        for (int t = 0; t < NSTEP; ++t, vrow += DXROW) {
            const f32x4 va = *(const f32x4*)(vrow);        // v0..v3 (uniform)
            const f32x4 vb = *(const f32x4*)(vrow + 4);    // v4..v7 (uniform)
            const f32x2 vc = *(const f32x2*)(vrow + 8);    // v8,v9  (uniform)
            const f32x2 vjp = *(const f32x2*)(vrow + j0);  // vj for q0,q1 (LDS)

            // Register extraction (no LDS): via = vv[ia], vk = (vv[k0], vv[k0+5])
            float via = va.x;
            via = ia1 ? va.y : via;
            via = ia2 ? va.z : via;
            via = ia3 ? va.w : via;
            via = ia4 ? vb.x : via;
            via = ia5 ? vb.y : via;
            via = ia6 ? vb.z : via;
            via = ia7 ? vb.w : via;
            via = ia8 ? vc.x : via;
            via = ia9 ? vc.y : via;

            float vk0v = va.x;
            vk0v = k1m ? va.y : vk0v;
            vk0v = k2m ? va.z : vk0v;
            vk0v = k3m ? va.w : vk0v;
            vk0v = k4m ? vb.x : vk0v;

            float vk1v = vb.y;
            vk1v = k1m ? vb.z : vk1v;
            vk1v = k2m ? vb.w : vk1v;
            vk1v = k3m ? vc.x : vk1v;
            vk1v = k4m ? vc.y : vk1v;

            f32x2 vkp;
            vkp.x = vk0v;
            vkp.y = vk1v;

            const f32x2 vv2[5] = {va.xy, va.zw, vb.xy, vb.zw, vc};

            // scalar prefix terms
            const float t3  = fmaf(via, 0.5f, s1a);
            const float t1b = fmaf(via, 0.25f, s1a) * (1.0f / 3.0f);
            const float t2b = fmaf(via, (1.0f / 3.0f), s1a) * 0.5f;
            f32x2 pA; pA.x = t1b; pA.y = t2b;
            f32x2 pT; pT.x = t3;  pT.y = t3;

            f32x2 vkhp;                       // (vk0*0.5, vk1*0.5)
            PK_MUL_HALF(vkhp, vkp);

            // level 2 (q-pairs)
            f32x2 a2p, b2p;
            PK_FMA_B0N(a2p, pA, vjp, s2p);    // a2_q = t1b*vj_q + s2_q
            PK_FMA_B1N(b2p, pA, vjp, s2p);    // b2_q = t2b*vj_q + s2_q
            PK_FMA_B0(s2p, pT, vjp);          // s2_q += t3*vj_q

            // level 3 (q-pairs, k-channel broadcast from vkp/vkhp halves)
            f32x2 a3xp, a3yp;
            PK_FMA_S1B0N(a3xp, a2p, vkhp, s3p[0]);  // a3_q@k0
            PK_FMA_S1B1N(a3yp, a2p, vkhp, s3p[1]);  // a3_q@k1
            PK_FMA_S1B0(s3p[0], b2p, vkp);          // s3_q@k0 += b2_q*vk0
            PK_FMA_S1B1(s3p[1], b2p, vkp);          // s3_q@k1 += b2_q*vk1

            // level 4: 20 pk-FMAs (a3 broadcast from pair halves)
            #pragma unroll
            for (int i = 0; i < 5; ++i) {
                PK_FMA_B0(acc2[0][i], a3xp, vv2[i]);
                PK_FMA_B1(acc2[1][i], a3xp, vv2[i]);
                PK_FMA_B0(acc2[2][i], a3yp, vv2[i]);
                PK_FMA_B1(acc2[3][i], a3yp, vv2[i]);
            }
            s1a += via;
        }
    }

    // ---- Epilogue: signed single-path row ----
    if (store_mode) {
        float* row = ws + (size_t)bp * DTOT;
        if (tid < D1)
            row[tid] = sgn * (path[(T_LEN - 1) * C_DIM + tid] - path[tid]);
        if (tid < 50) {       // k0 == 0 threads own ij0 = 2*tid
            row[D1 + ij0]     = sgn * s2p[0];
            row[D1 + ij0 + 1] = sgn * s2p[1];
        }
        if (tid < 250) {
            #pragma unroll
            for (int ch = 0; ch < 2; ++ch) {          // ch=0 -> k0, ch=1 -> k0+5
                const int kk = k0 + 5 * ch;
                #pragma unroll
                for (int q = 0; q < 2; ++q) {
                    const int idx3 = (ij0 + q) * 10 + kk;
                    row[D1 + D2 + idx3] = sgn * s3p[ch][q];
                    float* p4 = row + D1 + D2 + D3 + (size_t)idx3 * 10;
                    #pragma unroll
                    for (int i = 0; i < 5; ++i)
                        *(f32x2*)&p4[2 * i] = sgn * acc2[ch * 2 + q][i];
                }
            }
        }
    } else {
        float* base = ws + (size_t)(b % nrep) * DTOT;
        if (tid < D1)
            atomicAdd(&base[tid],
                      sgn * (path[(T_LEN - 1) * C_DIM + tid] - path[tid]));
        if (tid < 50) {
            atomicAdd(&base[D1 + ij0],     sgn * s2p[0]);
            atomicAdd(&base[D1 + ij0 + 1], sgn * s2p[1]);
        }
        if (tid < 250) {
            #pragma unroll
            for (int ch = 0; ch < 2; ++ch) {
                const int kk = k0 + 5 * ch;
                #pragma unroll
                for (int q = 0; q < 2; ++q) {
                    const int idx3 = (ij0 + q) * 10 + kk;
                    atomicAdd(&base[D1 + D2 + idx3], sgn * s3p[ch][q]);
                    #pragma unroll
                    for (int l = 0; l < 10; ++l)
                        atomicAdd(&base[D1 + D2 + D3 + idx3 * 10 + l],
                                  sgn * acc2[ch * 2 + q][l >> 1][l & 1]);
                }
            }
        }
    }
}

// Stage 1: block sums 32 rows for a float2 d-tile (coalesced), atomically
// accumulates into accvec[DTOT]. Grid: (ceil(5555/256), nrows/32).
__global__ __launch_bounds__(256) void sig_sum_kernel(
    const float* __restrict__ ws, float* __restrict__ accvec)
{
    const int d2 = blockIdx.x * 256 + threadIdx.x;   // DTOT/2 = 5555
    if (d2 >= DTOT / 2) return;
    const float* p = ws + (size_t)(blockIdx.y * 32) * DTOT + 2 * d2;
    float sx = 0.0f, sy = 0.0f;
    #pragma unroll
    for (int r = 0; r < 32; ++r) {
        const float2 v = *(const float2*)(p + (size_t)r * DTOT);
        sx += v.x; sy += v.y;
    }
    atomicAdd(&accvec[2 * d2], sx);
    atomicAdd(&accvec[2 * d2 + 1], sy);
}

// Stage 2: sum of squares -> sumsq; last block writes the norm.
__global__ __launch_bounds__(256) void sig_sumsq_kernel(
    const float* __restrict__ accvec, float* __restrict__ sumsq,
    unsigned int* __restrict__ counter, float* __restrict__ out, int nblocks)
{
    const int d = blockIdx.x * 256 + threadIdx.x;
    float s = 0.0f;
    if (d < DTOT) { float v = accvec[d]; s = v * v; }
    for (int off = 32; off > 0; off >>= 1) s += __shfl_down(s, off, 64);
    __shared__ float red[4];
    __shared__ unsigned int lastflag;
    if ((threadIdx.x & 63) == 0) red[threadIdx.x >> 6] = s;
    __syncthreads();
    if (threadIdx.x == 0) {
        atomicAdd(sumsq, red[0] + red[1] + red[2] + red[3]);
        __threadfence();
        lastflag = (atomicAdd(counter, 1u) == (unsigned int)(nblocks - 1));
    }
    __syncthreads();
    if (threadIdx.x == 0 && lastflag) {
        __threadfence();
        out[0] = sqrtf(*(volatile float*)sumsq) * (1.0f / (float)BSZ);
    }
}

// Fallback reduce for small-ws atomic-replica modes.
__global__ __launch_bounds__(256) void sig_reduce_kernel(
    const float* __restrict__ ws, int nrows, float* __restrict__ sumsq,
    unsigned int* __restrict__ counter, float* __restrict__ out, int nblocks)
{
    const int d = blockIdx.x * 256 + threadIdx.x;
    float s = 0.0f;
    if (d < DTOT) {
        for (int r = 0; r < nrows; ++r) s += ws[(size_t)r * DTOT + d];
        s = s * s;
    }
    for (int off = 32; off > 0; off >>= 1) s += __shfl_down(s, off, 64);
    __shared__ float red[4];
    __shared__ unsigned int lastflag;
    if ((threadIdx.x & 63) == 0) red[threadIdx.x >> 6] = s;
    __syncthreads();
    if (threadIdx.x == 0) {
        atomicAdd(sumsq, red[0] + red[1] + red[2] + red[3]);
        __threadfence();
        lastflag = (atomicAdd(counter, 1u) == (unsigned int)(nblocks - 1));
    }
    __syncthreads();
    if (threadIdx.x == 0 && lastflag) {
        __threadfence();
        out[0] = sqrtf(*(volatile float*)sumsq) * (1.0f / (float)BSZ);
    }
}

extern "C" void kernel_launch(void* const* d_in, const int* in_sizes, int n_in,
                              void* d_out, int out_size, void* d_ws, size_t ws_size,
                              hipStream_t stream) {
    const float* original   = (const float*)d_in[0];
    const float* generated  = (const float*)d_in[1];
    const int*   sample_idx = (const int*)d_in[2];
    float* out = (float*)d_out;
    float* ws  = (float*)d_ws;

    // Layouts:
    //  split: rows [0, 2N*DTOT), accvec [+DTOT), sumsq [+1), counter [+1)
    //  store: rows [0, N*DTOT),  accvec [+DTOT), sumsq [+1), counter [+1)
    const size_t need_split = ((size_t)(2 * NPAIR + 1) * DTOT + 2) * sizeof(float);
    const size_t need_store = ((size_t)(NPAIR + 1) * DTOT + 2) * sizeof(float);

    if (ws_size >= need_split) {
        // Primary: each pass-block writes its own signed row (no atomics).
        float* accvec = ws + (size_t)2 * NPAIR * DTOT;
        float* sumsq  = accvec + DTOT;
        unsigned int* counter = (unsigned int*)(sumsq + 1);
        hipMemsetAsync(accvec, 0, (DTOT + 2) * sizeof(float), stream);
        sig_accum_kernel<<<2 * NPAIR, 256, 0, stream>>>(original, generated,
                                                        sample_idx, ws, 1, 1);
        dim3 g1((DTOT / 2 + 255) / 256, 2 * NPAIR / 32);
        sig_sum_kernel<<<g1, 256, 0, stream>>>(ws, accvec);
        const int nb2 = (DTOT + 255) / 256;
        sig_sumsq_kernel<<<nb2, 256, 0, stream>>>(accvec, sumsq, counter, out, nb2);
    } else if (ws_size >= need_store) {
        // Pair-atomic: the two pass-blocks of a pair accumulate into one row.
        float* accvec = ws + (size_t)NPAIR * DTOT;
        float* sumsq  = accvec + DTOT;
        unsigned int* counter = (unsigned int*)(sumsq + 1);
        hipMemsetAsync(ws, 0, need_store, stream);
        sig_accum_kernel<<<2 * NPAIR, 256, 0, stream>>>(original, generated,
                                                        sample_idx, ws, NPAIR, 0);
        dim3 g1((DTOT / 2 + 255) / 256, NPAIR / 32);
        sig_sum_kernel<<<g1, 256, 0, stream>>>(ws, accvec);
        const int nb2 = (DTOT + 255) / 256;
        sig_sumsq_kernel<<<nb2, 256, 0, stream>>>(accvec, sumsq, counter, out, nb2);
    } else {
        int nrep = 1;
        if (ws_size >= ((size_t)64 * DTOT + 2) * sizeof(float)) nrep = 64;
        else if (ws_size >= ((size_t)8 * DTOT + 2) * sizeof(float)) nrep = 8;
        float* sumsq = ws + (size_t)nrep * DTOT;
        unsigned int* counter = (unsigned int*)(sumsq + 1);
        hipMemsetAsync(ws, 0, ((size_t)nrep * DTOT + 2) * sizeof(float), stream);
        sig_accum_kernel<<<2 * NPAIR, 256, 0, stream>>>(original, generated,
                                                        sample_idx, ws, nrep, 0);
        const int nb2 = (DTOT + 255) / 256;
        sig_reduce_kernel<<<nb2, 256, 0, stream>>>(ws, nrep, sumsq, counter, out, nb2);
    }
}

// Round 6
// 298.377 us; speedup vs baseline: 1.0518x; 1.0518x over previous
//
#include <hip/hip_runtime.h>

// SigWassersteinMetric: depth-4 path signature, C=10, T=256.
//   original: (4096, 256, 10) f32; generated: (1024, 256, 10) f32; sample_idx: (1024,)
//
// ROUND-20: pipe-balanced extraction -- vk0/vk1 via HOISTED-mask cndmask.
//   - R19 FAILED (240us): compiler re-materialized 13 v_cmp per step (masks
//     not hoisted) -> +66 VALU cyc/wave-step; VALU overshot to 1856 cyc/SIMD
//     while LDS fell to 1280 -> unbalanced + serial-chain slop.
//   - Calibrated model: time/CU-step = max(LDS cyc/wave x32, VALU cyc/wave x8).
//     R17: LDS 57x32=1824 binds (194us==measured). This round targets balance:
//       extract ONLY vk0/vk1 (8 cndmask, masks prebuilt once via __ballot ->
//       SGPR pairs, asm v_cndmask with "s" operand -> NO per-step compares)
//       LDS: 45.4x32 = 1453 ; VALU: 182x8 = 1456  -> ~155-180us accum.
//   - via and vjp STAY on LDS (extracting them over-rotates to VALU-bound).
//
// Horner-factored Chen step (verified rounds 2/4-13):
//   A2 = S2 + (S1 + v/4) (x) v/3 ;  B2 = S2 + (S1 + v/3) (x) v/2
//   A3 = S3 + A2 (x) v/2 ;  S4' = S4 + A3 (x) v ;  S3' = S3 + B2 (x) v
//   S2' = S2 + (S1 + v/2) (x) v ;  S1 closed-form in epilogue.
#define T_LEN 256
#define C_DIM 10
#define NSTEP 255
#define BSZ   1024
#define NPAIR 1024
#define D1 10
#define D2 100
#define D3 1000
#define DTOT 11110
#define PATH_ELEMS (T_LEN * C_DIM)   // 2560
#define DX_ELEMS (NSTEP * C_DIM)     // 2550
#define DXROW 12                     // padded dx row stride (48 B, 16B-aligned)

typedef float f32x2 __attribute__((ext_vector_type(2)));
typedef float f32x4 __attribute__((ext_vector_type(4)));

// d += bcast(a.lo) * b
#define PK_FMA_B0(d, a, b) \
    asm("v_pk_fma_f32 %0, %1, %2, %0 op_sel:[0,0,0] op_sel_hi:[0,1,1]" \
        : "+v"(d) : "v"(a), "v"(b))
// d += bcast(a.hi) * b
#define PK_FMA_B1(d, a, b) \
    asm("v_pk_fma_f32 %0, %1, %2, %0 op_sel:[1,0,0] op_sel_hi:[1,1,1]" \
        : "+v"(d) : "v"(a), "v"(b))
// d = bcast(a.lo) * b + c
#define PK_FMA_B0N(d, a, b, c) \
    asm("v_pk_fma_f32 %0, %1, %2, %3 op_sel:[0,0,0] op_sel_hi:[0,1,1]" \
        : "=v"(d) : "v"(a), "v"(b), "v"(c))
// d = bcast(a.hi) * b + c
#define PK_FMA_B1N(d, a, b, c) \
    asm("v_pk_fma_f32 %0, %1, %2, %3 op_sel:[1,0,0] op_sel_hi:[1,1,1]" \
        : "=v"(d) : "v"(a), "v"(b), "v"(c))
// d = a * bcast(b.lo) + c   (src1 broadcast)
#define PK_FMA_S1B0N(d, a, b, c) \
    asm("v_pk_fma_f32 %0, %1, %2, %3 op_sel:[0,0,0] op_sel_hi:[1,0,1]" \
        : "=v"(d) : "v"(a), "v"(b), "v"(c))
// d = a * bcast(b.hi) + c
#define PK_FMA_S1B1N(d, a, b, c) \
    asm("v_pk_fma_f32 %0, %1, %2, %3 op_sel:[0,1,0] op_sel_hi:[1,1,1]" \
        : "=v"(d) : "v"(a), "v"(b), "v"(c))
// d += a * bcast(b.lo)
#define PK_FMA_S1B0(d, a, b) \
    asm("v_pk_fma_f32 %0, %1, %2, %0 op_sel:[0,0,0] op_sel_hi:[1,0,1]" \
        : "+v"(d) : "v"(a), "v"(b))
// d += a * bcast(b.hi)
#define PK_FMA_S1B1(d, a, b) \
    asm("v_pk_fma_f32 %0, %1, %2, %0 op_sel:[0,1,0] op_sel_hi:[1,1,1]" \
        : "+v"(d) : "v"(a), "v"(b))
// d = a * 0.5 (both halves)
#define PK_MUL_HALF(d, a) \
    asm("v_pk_mul_f32 %0, %1, 0.5 op_sel:[0,0] op_sel_hi:[1,0]" \
        : "=v"(d) : "v"(a))
// dst = mask ? src : dst   (mask = pre-built wave ballot in SGPR pair)
#define SELM(dst, src, mask) \
    asm("v_cndmask_b32 %0, %0, %1, %2" \
        : "+v"(dst) : "v"(src), "s"(mask))

__global__ __launch_bounds__(256)
void sig_accum_kernel(
    const float* __restrict__ original,
    const float* __restrict__ generated,
    const int* __restrict__ sample_idx,
    float* __restrict__ ws, int nrep, int store_mode)
{
    const int tid  = threadIdx.x;
    const int bp   = blockIdx.x;         // 0 .. 2*NPAIR-1
    const int b    = bp >> 1;            // pair index
    const int pass = bp & 1;             // 0 = generated (-), 1 = original (+)
    const float sgn = pass ? 1.0f : -1.0f;

    __shared__ __align__(16) float s_dx[NSTEP * DXROW];  // 12240 B

    const float* path = pass
        ? original + (size_t)sample_idx[b] * PATH_ELEMS
        : generated + (size_t)b * PATH_ELEMS;

    for (int idx = tid; idx < DX_ELEMS; idx += 256) {
        int t = idx / C_DIM, c = idx - t * C_DIM;
        s_dx[t * DXROW + c] = path[idx + C_DIM] - path[idx];
    }
    __syncthreads();

    const int mbase = 2 * tid;               // valid tid<250
    const int k0  = mbase / 100;             // 0..4
    const int ij0 = mbase - k0 * 100;        // even
    const int ia  = ij0 / 10;
    const int j0  = ij0 - ia * 10;           // even -> (j0, j0+1) same decade

    float s1a = 0.0f;
    f32x2 s2p = {0.0f, 0.0f};                 // (q0, q1)
    f32x2 s3p[2] = {{0.0f, 0.0f}, {0.0f, 0.0f}};  // [0]=(q0,q1)@k0, [1]=@k1
    f32x2 acc2[4][5];                         // [0]=q0k0 [1]=q1k0 [2]=q0k1 [3]=q1k1
    #pragma unroll
    for (int r = 0; r < 4; ++r)
        #pragma unroll
        for (int i = 0; i < 5; ++i) acc2[r][i] = (f32x2){0.0f, 0.0f};

    if (tid < 250) {
        // Wave-uniform selection masks, built ONCE (SGPR pairs; each use
        // below is a single VOP3 v_cndmask with the pair as the mask).
        const unsigned long long mk1 = __ballot(k0 >= 1);
        const unsigned long long mk2 = __ballot(k0 >= 2);
        const unsigned long long mk3 = __ballot(k0 >= 3);
        const unsigned long long mk4 = __ballot(k0 >= 4);

        const float* vrow = s_dx;
        #pragma unroll 2
        for (int t = 0; t < NSTEP; ++t, vrow += DXROW) {
            const f32x4 va = *(const f32x4*)(vrow);        // v0..v3 (uniform)
            const f32x4 vb = *(const f32x4*)(vrow + 4);    // v4..v7 (uniform)
            const f32x2 vc = *(const f32x2*)(vrow + 8);    // v8,v9  (uniform)
            const f32x2 vjp = *(const f32x2*)(vrow + j0);  // vj for q0,q1 (LDS)
            const float via = vrow[ia];                    // (LDS b32)

            // vk0 = vv[k0], vk1 = vv[k0+5]: extracted from the uniform row
            // already in registers -- 8 cndmasks, no LDS, no per-step cmps.
            float vk0v = va.x;
            SELM(vk0v, va.y, mk1);
            SELM(vk0v, va.z, mk2);
            SELM(vk0v, va.w, mk3);
            SELM(vk0v, vb.x, mk4);
            float vk1v = vb.y;
            SELM(vk1v, vb.z, mk1);
            SELM(vk1v, vb.w, mk2);
            SELM(vk1v, vc.x, mk3);
            SELM(vk1v, vc.y, mk4);

            f32x2 vkp;
            vkp.x = vk0v;
            vkp.y = vk1v;

            const f32x2 vv2[5] = {va.xy, va.zw, vb.xy, vb.zw, vc};

            // scalar prefix terms
            const float t3  = fmaf(via, 0.5f, s1a);
            const float t1b = fmaf(via, 0.25f, s1a) * (1.0f / 3.0f);
            const float t2b = fmaf(via, (1.0f / 3.0f), s1a) * 0.5f;
            f32x2 pA; pA.x = t1b; pA.y = t2b;
            f32x2 pT; pT.x = t3;  pT.y = t3;

            f32x2 vkhp;                       // (vk0*0.5, vk1*0.5)
            PK_MUL_HALF(vkhp, vkp);

            // level 2 (q-pairs)
            f32x2 a2p, b2p;
            PK_FMA_B0N(a2p, pA, vjp, s2p);    // a2_q = t1b*vj_q + s2_q
            PK_FMA_B1N(b2p, pA, vjp, s2p);    // b2_q = t2b*vj_q + s2_q
            PK_FMA_B0(s2p, pT, vjp);          // s2_q += t3*vj_q

            // level 3 (q-pairs, k-channel broadcast from vkp/vkhp halves)
            f32x2 a3xp, a3yp;
            PK_FMA_S1B0N(a3xp, a2p, vkhp, s3p[0]);  // a3_q@k0
            PK_FMA_S1B1N(a3yp, a2p, vkhp, s3p[1]);  // a3_q@k1
            PK_FMA_S1B0(s3p[0], b2p, vkp);          // s3_q@k0 += b2_q*vk0
            PK_FMA_S1B1(s3p[1], b2p, vkp);          // s3_q@k1 += b2_q*vk1

            // level 4: 20 pk-FMAs (a3 broadcast from pair halves)
            #pragma unroll
            for (int i = 0; i < 5; ++i) {
                PK_FMA_B0(acc2[0][i], a3xp, vv2[i]);
                PK_FMA_B1(acc2[1][i], a3xp, vv2[i]);
                PK_FMA_B0(acc2[2][i], a3yp, vv2[i]);
                PK_FMA_B1(acc2[3][i], a3yp, vv2[i]);
            }
            s1a += via;
        }
    }

    // ---- Epilogue: signed single-path row ----
    if (store_mode) {
        float* row = ws + (size_t)bp * DTOT;
        if (tid < D1)
            row[tid] = sgn * (path[(T_LEN - 1) * C_DIM + tid] - path[tid]);
        if (tid < 50) {       // k0 == 0 threads own ij0 = 2*tid
            row[D1 + ij0]     = sgn * s2p[0];
            row[D1 + ij0 + 1] = sgn * s2p[1];
        }
        if (tid < 250) {
            #pragma unroll
            for (int ch = 0; ch < 2; ++ch) {          // ch=0 -> k0, ch=1 -> k0+5
                const int kk = k0 + 5 * ch;
                #pragma unroll
                for (int q = 0; q < 2; ++q) {
                    const int idx3 = (ij0 + q) * 10 + kk;
                    row[D1 + D2 + idx3] = sgn * s3p[ch][q];
                    float* p4 = row + D1 + D2 + D3 + (size_t)idx3 * 10;
                    #pragma unroll
                    for (int i = 0; i < 5; ++i)
                        *(f32x2*)&p4[2 * i] = sgn * acc2[ch * 2 + q][i];
                }
            }
        }
    } else {
        float* base = ws + (size_t)(b % nrep) * DTOT;
        if (tid < D1)
            atomicAdd(&base[tid],
                      sgn * (path[(T_LEN - 1) * C_DIM + tid] - path[tid]));
        if (tid < 50) {
            atomicAdd(&base[D1 + ij0],     sgn * s2p[0]);
            atomicAdd(&base[D1 + ij0 + 1], sgn * s2p[1]);
        }
        if (tid < 250) {
            #pragma unroll
            for (int ch = 0; ch < 2; ++ch) {
                const int kk = k0 + 5 * ch;
                #pragma unroll
                for (int q = 0; q < 2; ++q) {
                    const int idx3 = (ij0 + q) * 10 + kk;
                    atomicAdd(&base[D1 + D2 + idx3], sgn * s3p[ch][q]);
                    #pragma unroll
                    for (int l = 0; l < 10; ++l)
                        atomicAdd(&base[D1 + D2 + D3 + idx3 * 10 + l],
                                  sgn * acc2[ch * 2 + q][l >> 1][l & 1]);
                }
            }
        }
    }
}

// Stage 1: block sums 32 rows for a float2 d-tile (coalesced), atomically
// accumulates into accvec[DTOT]. Grid: (ceil(5555/256), nrows/32).
__global__ __launch_bounds__(256) void sig_sum_kernel(
    const float* __restrict__ ws, float* __restrict__ accvec)
{
    const int d2 = blockIdx.x * 256 + threadIdx.x;   // DTOT/2 = 5555
    if (d2 >= DTOT / 2) return;
    const float* p = ws + (size_t)(blockIdx.y * 32) * DTOT + 2 * d2;
    float sx = 0.0f, sy = 0.0f;
    #pragma unroll
    for (int r = 0; r < 32; ++r) {
        const float2 v = *(const float2*)(p + (size_t)r * DTOT);
        sx += v.x; sy += v.y;
    }
    atomicAdd(&accvec[2 * d2], sx);
    atomicAdd(&accvec[2 * d2 + 1], sy);
}

// Stage 2: sum of squares -> sumsq; last block writes the norm.
__global__ __launch_bounds__(256) void sig_sumsq_kernel(
    const float* __restrict__ accvec, float* __restrict__ sumsq,
    unsigned int* __restrict__ counter, float* __restrict__ out, int nblocks)
{
    const int d = blockIdx.x * 256 + threadIdx.x;
    float s = 0.0f;
    if (d < DTOT) { float v = accvec[d]; s = v * v; }
    for (int off = 32; off > 0; off >>= 1) s += __shfl_down(s, off, 64);
    __shared__ float red[4];
    __shared__ unsigned int lastflag;
    if ((threadIdx.x & 63) == 0) red[threadIdx.x >> 6] = s;
    __syncthreads();
    if (threadIdx.x == 0) {
        atomicAdd(sumsq, red[0] + red[1] + red[2] + red[3]);
        __threadfence();
        lastflag = (atomicAdd(counter, 1u) == (unsigned int)(nblocks - 1));
    }
    __syncthreads();
    if (threadIdx.x == 0 && lastflag) {
        __threadfence();
        out[0] = sqrtf(*(volatile float*)sumsq) * (1.0f / (float)BSZ);
    }
}

// Fallback reduce for small-ws atomic-replica modes.
__global__ __launch_bounds__(256) void sig_reduce_kernel(
    const float* __restrict__ ws, int nrows, float* __restrict__ sumsq,
    unsigned int* __restrict__ counter, float* __restrict__ out, int nblocks)
{
    const int d = blockIdx.x * 256 + threadIdx.x;
    float s = 0.0f;
    if (d < DTOT) {
        for (int r = 0; r < nrows; ++r) s += ws[(size_t)r * DTOT + d];
        s = s * s;
    }
    for (int off = 32; off > 0; off >>= 1) s += __shfl_down(s, off, 64);
    __shared__ float red[4];
    __shared__ unsigned int lastflag;
    if ((threadIdx.x & 63) == 0) red[threadIdx.x >> 6] = s;
    __syncthreads();
    if (threadIdx.x == 0) {
        atomicAdd(sumsq, red[0] + red[1] + red[2] + red[3]);
        __threadfence();
        lastflag = (atomicAdd(counter, 1u) == (unsigned int)(nblocks - 1));
    }
    __syncthreads();
    if (threadIdx.x == 0 && lastflag) {
        __threadfence();
        out[0] = sqrtf(*(volatile float*)sumsq) * (1.0f / (float)BSZ);
    }
}

extern "C" void kernel_launch(void* const* d_in, const int* in_sizes, int n_in,
                              void* d_out, int out_size, void* d_ws, size_t ws_size,
                              hipStream_t stream) {
    const float* original   = (const float*)d_in[0];
    const float* generated  = (const float*)d_in[1];
    const int*   sample_idx = (const int*)d_in[2];
    float* out = (float*)d_out;
    float* ws  = (float*)d_ws;

    // Layouts:
    //  split: rows [0, 2N*DTOT), accvec [+DTOT), sumsq [+1), counter [+1)
    //  store: rows [0, N*DTOT),  accvec [+DTOT), sumsq [+1), counter [+1)
    const size_t need_split = ((size_t)(2 * NPAIR + 1) * DTOT + 2) * sizeof(float);
    const size_t need_store = ((size_t)(NPAIR + 1) * DTOT + 2) * sizeof(float);

    if (ws_size >= need_split) {
        // Primary: each pass-block writes its own signed row (no atomics).
        float* accvec = ws + (size_t)2 * NPAIR * DTOT;
        float* sumsq  = accvec + DTOT;
        unsigned int* counter = (unsigned int*)(sumsq + 1);
        hipMemsetAsync(accvec, 0, (DTOT + 2) * sizeof(float), stream);
        sig_accum_kernel<<<2 * NPAIR, 256, 0, stream>>>(original, generated,
                                                        sample_idx, ws, 1, 1);
        dim3 g1((DTOT / 2 + 255) / 256, 2 * NPAIR / 32);
        sig_sum_kernel<<<g1, 256, 0, stream>>>(ws, accvec);
        const int nb2 = (DTOT + 255) / 256;
        sig_sumsq_kernel<<<nb2, 256, 0, stream>>>(accvec, sumsq, counter, out, nb2);
    } else if (ws_size >= need_store) {
        // Pair-atomic: the two pass-blocks of a pair accumulate into one row.
        float* accvec = ws + (size_t)NPAIR * DTOT;
        float* sumsq  = accvec + DTOT;
        unsigned int* counter = (unsigned int*)(sumsq + 1);
        hipMemsetAsync(ws, 0, need_store, stream);
        sig_accum_kernel<<<2 * NPAIR, 256, 0, stream>>>(original, generated,
                                                        sample_idx, ws, NPAIR, 0);
        dim3 g1((DTOT / 2 + 255) / 256, NPAIR / 32);
        sig_sum_kernel<<<g1, 256, 0, stream>>>(ws, accvec);
        const int nb2 = (DTOT + 255) / 256;
        sig_sumsq_kernel<<<nb2, 256, 0, stream>>>(accvec, sumsq, counter, out, nb2);
    } else {
        int nrep = 1;
        if (ws_size >= ((size_t)64 * DTOT + 2) * sizeof(float)) nrep = 64;
        else if (ws_size >= ((size_t)8 * DTOT + 2) * sizeof(float)) nrep = 8;
        float* sumsq = ws + (size_t)nrep * DTOT;
        unsigned int* counter = (unsigned int*)(sumsq + 1);
        hipMemsetAsync(ws, 0, ((size_t)nrep * DTOT + 2) * sizeof(float), stream);
        sig_accum_kernel<<<2 * NPAIR, 256, 0, stream>>>(original, generated,
                                                        sample_idx, ws, nrep, 0);
        const int nb2 = (DTOT + 255) / 256;
        sig_reduce_kernel<<<nb2, 256, 0, stream>>>(ws, nrep, sumsq, counter, out, nb2);
    }
}